// Round 4
// baseline (444.242 us; speedup 1.0000x reference)
//
#include <hip/hip_runtime.h>

// EncodecEuclideanCodebook — R4.
//   x: [131072, 128] fp32, embed: [1024, 128] fp32.
//   out: quantize [131072*128] f32, then embed_ind [131072] (indices as f32).
//
// score = 2*x.e - ||e||^2 (argmax-equivalent). Approx via K=256 bf16 GEMM:
// x_hi.e_hi + x_lo.e_hi (x_hi.e_lo dropped; |err| <~0.15 worst-case over all
// pairs). Rows with top2 gap < MARGIN=0.25 are appended to a worklist and
// re-scored exactly in fp32 by a compacted batch-GEMM refine pass.
// vq: x B-fragments register-resident (bh/bl), e-stages ping-pong in LDS with
// one barrier/stage + glds prefetch (R3 was LDS-read-pipe bound, 80 reads/chunk
// -> 16). Refine R3 was 160us (serial per-row embed re-reads) -> tiled GEMM.

#define N_ROWS (64 * 2048)
#define DIM 128
#define BINS 1024
#define MARGIN 0.25f

typedef __attribute__((ext_vector_type(8))) short short8;  // 8 bf16 = 4 VGPR
typedef __attribute__((ext_vector_type(4))) float f32x4;

__device__ __forceinline__ unsigned short f2bf(float f) {   // RNE fp32->bf16
    unsigned u = __float_as_uint(f);
    u += 0x7fffu + ((u >> 16) & 1u);
    return (unsigned short)(u >> 16);
}
__device__ __forceinline__ float bf2f(unsigned short h) {
    return __uint_as_float(((unsigned)h) << 16);
}
__device__ __forceinline__ void glds16(const void* g, void* l) {
    __builtin_amdgcn_global_load_lds((const __attribute__((address_space(1))) char*)g,
                                     (__attribute__((address_space(3))) char*)l, 16, 0, 0);
}

// e_img: 16 stages x 16 KB (hi only). Stage S = chunk*4 + ks holds bins
// [256*chunk,+256) x k [32*ks,+32); byte off = b*64 + 16*(g2 ^ ((b>>2)&3)).
__global__ __launch_bounds__(256) void prep_kernel(const float* __restrict__ embed,
                                                   short* __restrict__ e_img,
                                                   float* __restrict__ esq_g,
                                                   int* __restrict__ counter) {
    int bin = blockIdx.x * 256 + threadIdx.x;
    if (bin == 0) *counter = 0;                    // ws re-poisoned every launch
    const float4* e4 = (const float4*)(embed + (size_t)bin * DIM);
    int c = bin >> 8, b = bin & 255;
    float s = 0.f;
#pragma unroll
    for (int g = 0; g < 16; ++g) {
        float4 v0 = e4[2 * g], v1 = e4[2 * g + 1];
        s += v0.x * v0.x + v0.y * v0.y + v0.z * v0.z + v0.w * v0.w;
        s += v1.x * v1.x + v1.y * v1.y + v1.z * v1.z + v1.w * v1.w;
        float f[8] = {v0.x, v0.y, v0.z, v0.w, v1.x, v1.y, v1.z, v1.w};
        short8 H;
#pragma unroll
        for (int j = 0; j < 8; ++j) H[j] = (short)f2bf(f[j]);
        int ks = g >> 2, g2 = g & 3;
        size_t off = ((size_t)(c * 4 + ks) << 14) + (size_t)b * 64 + 16 * (g2 ^ ((b >> 2) & 3));
        *(short8*)((char*)e_img + off) = H;
    }
    esq_g[bin] = s;
}

__global__ __launch_bounds__(256, 2) void vq_mfma_kernel(const float* __restrict__ x,
                                                         const short* __restrict__ e_img,
                                                         const float* __restrict__ esq_g,
                                                         float* __restrict__ out_idx,
                                                         int* __restrict__ list,
                                                         int* __restrict__ counter) {
    __shared__ __align__(16) short smem[16384];   // 32 KB: xh|xl conv, then ebuf ping-pong
    short* xh_s = smem;            // 16 KB
    short* xl_s = smem + 8192;     // 16 KB

    const int t = threadIdx.x;
    const int wv = t >> 6, lane = t & 63, q = lane >> 4, L15 = lane & 15;
    const int R0 = blockIdx.x * 64;

    // ---- convert x tile -> bf16 hi/lo in LDS (swizzled: group g at g^(row&7)) ----
    {
        const float4* xg = (const float4*)(x + (size_t)R0 * DIM);
#pragma unroll
        for (int qq = 0; qq < 4; ++qq) {
            int G = qq * 256 + t;
            int row = G >> 4, g = G & 15;
            float4 v0 = xg[row * 32 + 2 * g];
            float4 v1 = xg[row * 32 + 2 * g + 1];
            float f[8] = {v0.x, v0.y, v0.z, v0.w, v1.x, v1.y, v1.z, v1.w};
            short8 H, L;
#pragma unroll
            for (int j = 0; j < 8; ++j) {
                unsigned short h = f2bf(f[j]);
                H[j] = (short)h;
                L[j] = (short)f2bf(f[j] - bf2f(h));
            }
            int off = row * 256 + 16 * (g ^ (row & 7));
            *(short8*)((char*)xh_s + off) = H;
            *(short8*)((char*)xl_s + off) = L;
        }
    }
    __syncthreads();

    // ---- preload x B-fragments into registers (layout identical to R3 reads) ----
    short8 bh[4][4], bl[4][4];
#pragma unroll
    for (int ks = 0; ks < 4; ++ks) {
        const int sB = 16 * ((((ks << 2) | q)) ^ (lane & 7));
#pragma unroll
        for (int nt = 0; nt < 4; ++nt) {
            bh[ks][nt] = *(const short8*)((const char*)xh_s + (16 * nt + L15) * 256 + sB);
            bl[ks][nt] = *(const short8*)((const char*)xl_s + (16 * nt + L15) * 256 + sB);
        }
    }
    __syncthreads();   // conversion buffers now dead -> reuse as ebuf[2]

    const int sA = 16 * (q ^ ((L15 >> 2) & 3));
    const int aOff = (64 * wv + L15) * 64 + sA;

    // prefetch stage 0
    {
        const char* src = (const char*)e_img;
#pragma unroll
        for (int i = 0; i < 4; ++i) {
            int off = ((i << 2) | wv) << 10;
            glds16(src + off + lane * 16, (char*)smem + off);
        }
    }

    float best[4], sec[4];
    int bidx[4];
#pragma unroll
    for (int nt = 0; nt < 4; ++nt) { best[nt] = -3.4e38f; sec[nt] = -3.4e38f; bidx[nt] = 0; }

    for (int c = 0; c < 4; ++c) {                 // 4 chunks of 256 bins
        f32x4 acc[4][4];
#pragma unroll
        for (int mt = 0; mt < 4; ++mt)
#pragma unroll
            for (int nt = 0; nt < 4; ++nt) acc[mt][nt] = (f32x4){0.f, 0.f, 0.f, 0.f};

#pragma unroll
        for (int s = 0; s < 4; ++s) {             // 4 e_hi k-stages
            const int gs = c * 4 + s;
            __syncthreads();                      // stage gs landed; prev readers done
            if (gs < 15) {                        // prefetch next stage into other half
                const char* src = (const char*)e_img + ((size_t)(gs + 1) << 14);
                char* dst = (char*)(smem + ((gs + 1) & 1) * 8192);
#pragma unroll
                for (int i = 0; i < 4; ++i) {
                    int off = ((i << 2) | wv) << 10;
                    glds16(src + off + lane * 16, dst + off);
                }
            }
            const char* buf = (const char*)(smem + (gs & 1) * 8192);
            short8 a[4];
#pragma unroll
            for (int mt = 0; mt < 4; ++mt)
                a[mt] = *(const short8*)(buf + aOff + mt * 1024);
#pragma unroll
            for (int mt = 0; mt < 4; ++mt)
#pragma unroll
                for (int nt = 0; nt < 4; ++nt)
                    acc[mt][nt] = __builtin_amdgcn_mfma_f32_16x16x32_bf16(a[mt], bh[s][nt], acc[mt][nt], 0, 0, 0);
#pragma unroll
            for (int mt = 0; mt < 4; ++mt)
#pragma unroll
                for (int nt = 0; nt < 4; ++nt)
                    acc[mt][nt] = __builtin_amdgcn_mfma_f32_16x16x32_bf16(a[mt], bl[s][nt], acc[mt][nt], 0, 0, 0);
        }

        // ---- chunk epilogue: score + per-lane top-2 (bins ascending) ----
        const float* ep = esq_g + 256 * c + 64 * wv + 4 * q;
#pragma unroll
        for (int mt = 0; mt < 4; ++mt)
#pragma unroll
            for (int r = 0; r < 4; ++r) {
                int bin = 256 * c + 64 * wv + 16 * mt + 4 * q + r;
                float e2 = ep[16 * mt + r];
#pragma unroll
                for (int nt = 0; nt < 4; ++nt) {
                    float sc = 2.f * acc[mt][nt][r] - e2;
                    if (sc > best[nt]) { sec[nt] = best[nt]; best[nt] = sc; bidx[nt] = bin; }
                    else if (sc > sec[nt]) sec[nt] = sc;
                }
            }
    }

    // ---- cross-quad top-2 merge ----
#pragma unroll
    for (int nt = 0; nt < 4; ++nt) {
        for (int off = 16; off <= 32; off <<= 1) {
            float ob = __shfl_xor(best[nt], off);
            float os = __shfl_xor(sec[nt], off);
            int oi = __shfl_xor(bidx[nt], off);
            if (ob > best[nt]) { sec[nt] = fmaxf(best[nt], os); best[nt] = ob; bidx[nt] = oi; }
            else sec[nt] = fmaxf(sec[nt], ob);
        }
    }
    __syncthreads();
    float* sv = (float*)smem;                     // [wave][64 rows][best,sec,idx]
    if (q == 0) {
#pragma unroll
        for (int nt = 0; nt < 4; ++nt) {
            int base = (wv * 64 + 16 * nt + L15) * 3;
            sv[base] = best[nt]; sv[base + 1] = sec[nt];
            ((int*)sv)[base + 2] = bidx[nt];
        }
    }
    __syncthreads();
    if (t < 64) {
        float b0 = sv[t * 3], s0 = sv[t * 3 + 1];
        int i0 = ((int*)sv)[t * 3 + 2];
        for (int w = 1; w < 4; ++w) {
            int base = (w * 64 + t) * 3;
            float ob = sv[base], os = sv[base + 1];
            int oi = ((int*)sv)[base + 2];
            if (ob > b0) { s0 = fmaxf(b0, os); b0 = ob; i0 = oi; }
            else s0 = fmaxf(s0, ob);
        }
        out_idx[R0 + t] = (float)i0;
        if (b0 - s0 < MARGIN) {
            int pos = atomicAdd(counter, 1);
            list[pos] = R0 + t;
        }
    }
}

// Compacted exact fp32 refine: 16 flagged rows x 1024 bins per tile, fixed grid,
// tiles grid-strided. First-max tie-break identical to reference semantics.
#define SWB(r, c4) ((r) * 128 + 4 * ((c4) ^ ((r) & 31)))
__global__ __launch_bounds__(256) void refine_kernel(const float* __restrict__ x,
                                                     const float* __restrict__ embed,
                                                     const float* __restrict__ esq_g,
                                                     float* __restrict__ out_idx,
                                                     const int* __restrict__ list,
                                                     const int* __restrict__ counter) {
    __shared__ float xr[16 * 128];    // 8 KB: 16 x-rows
    __shared__ float bs[64 * 128];    // 32 KB: 64-bin embed chunk, swizzled
    __shared__ int rowbuf[16];

    const int t = threadIdx.x;
    const int tx = t & 63;            // bin lane within chunk
    const int ty = t >> 6;            // row group (4 rows)
    const int F = *counter;

    for (int tile = blockIdx.x; tile * 16 < F; tile += gridDim.x) {
        const int base = tile * 16;
        __syncthreads();              // previous-iteration users done
        if (t < 16) rowbuf[t] = list[min(base + t, F - 1)];
        __syncthreads();
        // stage 16 x rows (512 float4, 2/thread)
#pragma unroll
        for (int i = 0; i < 2; ++i) {
            int f = i * 256 + t;
            int r = f >> 5, cc = f & 31;
            float4 v = ((const float4*)(x + (size_t)rowbuf[r] * DIM))[cc];
            *(float4*)&xr[r * 128 + cc * 4] = v;
        }

        float bb[4]; int bi[4];
#pragma unroll
        for (int rr = 0; rr < 4; ++rr) { bb[rr] = -3.4e38f; bi[rr] = 0; }

        for (int chunk = 0; chunk < 16; ++chunk) {
            __syncthreads();          // readers of previous chunk done
            // stage 64 bins x 128 (2048 float4, 8/thread), XOR-swizzled
            const float4* eg = (const float4*)(embed + (size_t)chunk * 64 * DIM);
#pragma unroll
            for (int i = 0; i < 8; ++i) {
                int f = i * 256 + t;
                int r = f >> 5, cc = f & 31;
                float4 v = eg[f];
                *(float4*)&bs[SWB(r, cc)] = v;
            }
            __syncthreads();

            float acc[4];
#pragma unroll
            for (int rr = 0; rr < 4; ++rr) acc[rr] = 0.f;
#pragma unroll 8
            for (int k4 = 0; k4 < 32; ++k4) {
                float4 b = *(const float4*)&bs[SWB(tx, k4)];
#pragma unroll
                for (int rr = 0; rr < 4; ++rr) {
                    float4 a = *(const float4*)&xr[(4 * ty + rr) * 128 + k4 * 4];
                    acc[rr] = fmaf(a.x, b.x, acc[rr]);
                    acc[rr] = fmaf(a.y, b.y, acc[rr]);
                    acc[rr] = fmaf(a.z, b.z, acc[rr]);
                    acc[rr] = fmaf(a.w, b.w, acc[rr]);
                }
            }
            const int bin = chunk * 64 + tx;
            const float e2 = esq_g[bin];
#pragma unroll
            for (int rr = 0; rr < 4; ++rr) {
                float sc = 2.f * acc[rr] - e2;
                if (sc > bb[rr]) { bb[rr] = sc; bi[rr] = bin; }   // chunks ascending
            }
        }

        // reduce over 64 bin-lanes per row
        __syncthreads();
        float* vals = bs;                 // [16][64]
        int* idxs = (int*)(bs + 1024);    // [16][64]
#pragma unroll
        for (int rr = 0; rr < 4; ++rr) {
            vals[(4 * ty + rr) * 64 + tx] = bb[rr];
            idxs[(4 * ty + rr) * 64 + tx] = bi[rr];
        }
        __syncthreads();
        if (t < 16 && base + t < F) {
            float bv = vals[t * 64];
            int bix = idxs[t * 64];
            for (int j = 1; j < 64; ++j) {
                float v = vals[t * 64 + j];
                int id = idxs[t * 64 + j];
                if (v > bv || (v == bv && id < bix)) { bv = v; bix = id; }
            }
            out_idx[rowbuf[t]] = (float)bix;
        }
    }
}

__global__ __launch_bounds__(256) void gather_kernel(const float* __restrict__ embed,
                                                     const float* __restrict__ out_idx,
                                                     float4* __restrict__ out_q4) {
    int gid = blockIdx.x * 256 + threadIdx.x;
    int row = gid >> 5, seg = gid & 31;
    int idx = (int)out_idx[row];
    out_q4[(size_t)row * 32 + seg] = ((const float4*)embed)[(size_t)idx * 32 + seg];
}

extern "C" void kernel_launch(void* const* d_in, const int* in_sizes, int n_in,
                              void* d_out, int out_size, void* d_ws, size_t ws_size,
                              hipStream_t stream) {
    const float* x = (const float*)d_in[0];
    const float* embed = (const float*)d_in[1];
    float* out_q = (float*)d_out;
    float* out_idx = out_q + (size_t)N_ROWS * DIM;
    char* wsb = (char*)d_ws;
    short* e_img = (short*)wsb;                               // 256 KB (16 stages x 16 KB)
    float* esq_g = (float*)(wsb + (16 << 14));                // 4 KB
    int* counter = (int*)(wsb + (16 << 14) + 4096);           // 4 B (+pad)
    int* list = (int*)(wsb + (16 << 14) + 4096 + 128);        // 512 KB

    prep_kernel<<<BINS / 256, 256, 0, stream>>>(embed, e_img, esq_g, counter);
    vq_mfma_kernel<<<N_ROWS / 64, 256, 0, stream>>>(x, e_img, esq_g, out_idx, list, counter);
    refine_kernel<<<256, 256, 0, stream>>>(x, embed, esq_g, out_idx, list, counter);
    gather_kernel<<<(N_ROWS * 32) / 256, 256, 0, stream>>>(embed, out_idx, (float4*)out_q);
}

// Round 5
// 358.917 us; speedup vs baseline: 1.2377x; 1.2377x over previous
//
#include <hip/hip_runtime.h>

// EncodecEuclideanCodebook — R5.
//   x: [131072, 128] fp32, embed: [1024, 128] fp32.
//   out: quantize [131072*128] f32, then embed_ind [131072] (indices as f32).
//
// score = 2*x.e - ||e||^2 (argmax-equivalent). Approx: K=256 fp16 MFMA GEMM
// (x_hi + x_lo) . fp16(e); only dropped term is 2*x.(e - fp16(e)),
// sigma ~ 0.0063 -> MARGIN 0.05 = 8 sigma. Flagged rows (est ~3%) re-scored
// exactly in fp32. Gather fused into vq/refine epilogues (no 4th kernel).
//
// R4 lessons: (a) __launch_bounds__ 2nd arg is only a MIN waves/EU -> compiler
// targeted 4 waves/EU and spilled bh/bl (VGPR=128, WRITE_SIZE=111MB). Fixed
// with amdgpu_waves_per_eu(2,2). (b) bf16 needed margin 0.25 -> ~15% flagged
// -> fp32 refine floor ~30us+. fp16 gives 40x smaller error at same MFMA rate.

#define N_ROWS (64 * 2048)
#define DIM 128
#define BINS 1024
#define MARGIN 0.05f

typedef __attribute__((ext_vector_type(8))) _Float16 half8;  // 16 B = 4 VGPR
typedef __attribute__((ext_vector_type(4))) float f32x4;

__device__ __forceinline__ void glds16(const void* g, void* l) {
    __builtin_amdgcn_global_load_lds((const __attribute__((address_space(1))) char*)g,
                                     (__attribute__((address_space(3))) char*)l, 16, 0, 0);
}

// e_img: 16 stages x 16 KB fp16. Stage S = chunk*4 + ks holds bins
// [256*chunk,+256) x k [32*ks,+32); byte off = b*64 + 16*(g2 ^ ((b>>2)&3)).
__global__ __launch_bounds__(256) void prep_kernel(const float* __restrict__ embed,
                                                   _Float16* __restrict__ e_img,
                                                   float* __restrict__ esq_g,
                                                   int* __restrict__ counter) {
    int bin = blockIdx.x * 256 + threadIdx.x;
    if (bin == 0) *counter = 0;
    const float4* e4 = (const float4*)(embed + (size_t)bin * DIM);
    int c = bin >> 8, b = bin & 255;
    float s = 0.f;
#pragma unroll
    for (int g = 0; g < 16; ++g) {
        float4 v0 = e4[2 * g], v1 = e4[2 * g + 1];
        s += v0.x * v0.x + v0.y * v0.y + v0.z * v0.z + v0.w * v0.w;
        s += v1.x * v1.x + v1.y * v1.y + v1.z * v1.z + v1.w * v1.w;
        float f[8] = {v0.x, v0.y, v0.z, v0.w, v1.x, v1.y, v1.z, v1.w};
        half8 H;
#pragma unroll
        for (int j = 0; j < 8; ++j) H[j] = (_Float16)f[j];
        int ks = g >> 2, g2 = g & 3;
        size_t off = ((size_t)(c * 4 + ks) << 14) + (size_t)b * 64 + 16 * (g2 ^ ((b >> 2) & 3));
        *(half8*)((char*)e_img + off) = H;
    }
    esq_g[bin] = s;
}

// 512 threads = 8 waves. Wave wv: row-half h = wv>>2 (64 rows), bin-quarter
// bq = wv&3 (64 bins of each 256-bin chunk). Wave tile 64 bins x 64 rows.
__global__ __launch_bounds__(512) __attribute__((amdgpu_waves_per_eu(2, 2)))
void vq_mfma_kernel(const float* __restrict__ x,
                    const _Float16* __restrict__ e_img,
                    const float* __restrict__ esq_g,
                    const float* __restrict__ embed,
                    float* __restrict__ out_idx,
                    float* __restrict__ out_q,
                    int* __restrict__ list,
                    int* __restrict__ counter) {
    __shared__ __align__(16) char smem[65536];
    char* xh_s = smem;            // 32 KB [128 rows][256 B], swizzled
    char* xl_s = smem + 32768;    // 32 KB
    // after B-frag preload: smem[0..32K) reused as e-stage ping-pong (2x16KB)

    const int t = threadIdx.x;
    const int wv = t >> 6, lane = t & 63, q = lane >> 4, L15 = lane & 15;
    const int h = wv >> 2, bq = wv & 3;
    const int R0 = blockIdx.x * 128;

    // ---- convert x tile -> fp16 hi/lo in LDS (group g stored at g^(row&7)) ----
    {
        const float4* xg = (const float4*)(x + (size_t)R0 * DIM);
#pragma unroll
        for (int qq = 0; qq < 4; ++qq) {
            int G = qq * 512 + t;
            int row = G >> 4, g = G & 15;
            float4 v0 = xg[row * 32 + 2 * g];
            float4 v1 = xg[row * 32 + 2 * g + 1];
            float f[8] = {v0.x, v0.y, v0.z, v0.w, v1.x, v1.y, v1.z, v1.w};
            half8 H, L;
#pragma unroll
            for (int j = 0; j < 8; ++j) {
                _Float16 hv = (_Float16)f[j];
                H[j] = hv;
                L[j] = (_Float16)(f[j] - (float)hv);
            }
            int off = row * 256 + 16 * (g ^ (row & 7));
            *(half8*)(xh_s + off) = H;
            *(half8*)(xl_s + off) = L;
        }
    }
    __syncthreads();

    // ---- preload x B-fragments: rows 64h+16nt+L15, k-group (ks<<2)|q ----
    half8 bh[4][4], bl[4][4];
#pragma unroll
    for (int ks = 0; ks < 4; ++ks) {
        const int sB = 16 * ((((ks << 2) | q)) ^ (L15 & 7));
#pragma unroll
        for (int nt = 0; nt < 4; ++nt) {
            int rb = (64 * h + 16 * nt + L15) * 256 + sB;
            bh[ks][nt] = *(const half8*)(xh_s + rb);
            bl[ks][nt] = *(const half8*)(xl_s + rb);
        }
    }
    __syncthreads();   // xh region dead -> ping-pong e-stage buffers

    const int sA = 16 * (q ^ ((L15 >> 2) & 3));
    const int aOff = (64 * bq + L15) * 64 + sA;

    // prefetch stage 0 (16 KB, 2 KB per wave: 2 wave-uniform 1KB segments)
    {
        const char* src = (const char*)e_img;
#pragma unroll
        for (int i = 0; i < 2; ++i) {
            int off = ((i << 3) | wv) << 10;
            glds16(src + off + lane * 16, smem + off);
        }
    }

    float best[4], sec[4];
    int bidx[4];
#pragma unroll
    for (int nt = 0; nt < 4; ++nt) { best[nt] = -3.4e38f; sec[nt] = -3.4e38f; bidx[nt] = 0; }

    for (int c = 0; c < 4; ++c) {                 // 4 chunks of 256 bins
        f32x4 acc[4][4];
#pragma unroll
        for (int mt = 0; mt < 4; ++mt)
#pragma unroll
            for (int nt = 0; nt < 4; ++nt) acc[mt][nt] = (f32x4){0.f, 0.f, 0.f, 0.f};

#pragma unroll
        for (int s = 0; s < 4; ++s) {             // 4 k-stages of 32
            const int gs = c * 4 + s;
            __syncthreads();                      // stage gs landed; prev readers done
            if (gs < 15) {
                const char* src = (const char*)e_img + ((size_t)(gs + 1) << 14);
                char* dst = smem + ((gs + 1) & 1) * 16384;
#pragma unroll
                for (int i = 0; i < 2; ++i) {
                    int off = ((i << 3) | wv) << 10;
                    glds16(src + off + lane * 16, dst + off);
                }
            }
            const char* buf = smem + (gs & 1) * 16384;
            half8 a[4];
#pragma unroll
            for (int mt = 0; mt < 4; ++mt)
                a[mt] = *(const half8*)(buf + aOff + mt * 1024);
#pragma unroll
            for (int mt = 0; mt < 4; ++mt)
#pragma unroll
                for (int nt = 0; nt < 4; ++nt)
                    acc[mt][nt] = __builtin_amdgcn_mfma_f32_16x16x32_f16(a[mt], bh[s][nt], acc[mt][nt], 0, 0, 0);
#pragma unroll
            for (int mt = 0; mt < 4; ++mt)
#pragma unroll
                for (int nt = 0; nt < 4; ++nt)
                    acc[mt][nt] = __builtin_amdgcn_mfma_f32_16x16x32_f16(a[mt], bl[s][nt], acc[mt][nt], 0, 0, 0);
        }

        // ---- chunk epilogue: per-lane top-2 over its 16 bins (ascending) ----
        const float* ep = esq_g + 256 * c + 64 * bq + 4 * q;
#pragma unroll
        for (int mt = 0; mt < 4; ++mt)
#pragma unroll
            for (int r = 0; r < 4; ++r) {
                int bin = 256 * c + 64 * bq + 16 * mt + 4 * q + r;
                float e2 = ep[16 * mt + r];
#pragma unroll
                for (int nt = 0; nt < 4; ++nt) {
                    float sc = 2.f * acc[mt][nt][r] - e2;
                    if (sc > best[nt]) { sec[nt] = best[nt]; best[nt] = sc; bidx[nt] = bin; }
                    else if (sc > sec[nt]) sec[nt] = sc;
                }
            }
    }

    // ---- cross-quad top-2 merge (within wave) ----
#pragma unroll
    for (int nt = 0; nt < 4; ++nt) {
        for (int off = 16; off <= 32; off <<= 1) {
            float ob = __shfl_xor(best[nt], off);
            float os = __shfl_xor(sec[nt], off);
            int oi = __shfl_xor(bidx[nt], off);
            if (ob > best[nt]) { sec[nt] = fmaxf(best[nt], os); best[nt] = ob; bidx[nt] = oi; }
            else sec[nt] = fmaxf(sec[nt], ob);
        }
    }
    __syncthreads();                              // ebuf dead -> scratch
    float* sv = (float*)smem;                     // [8 waves][64 rows][b,s,i]
    int* fidx = (int*)(smem + 8192);              // [128]
    if (q == 0) {
#pragma unroll
        for (int nt = 0; nt < 4; ++nt) {
            int base = (wv * 64 + 16 * nt + L15) * 3;
            sv[base] = best[nt]; sv[base + 1] = sec[nt];
            ((int*)sv)[base + 2] = bidx[nt];
        }
    }
    __syncthreads();
    if (t < 128) {
        int hh = t >> 6, r64 = t & 63;
        int b0w = 4 * hh;
        float b0 = sv[(b0w * 64 + r64) * 3], s0 = sv[(b0w * 64 + r64) * 3 + 1];
        int i0 = ((int*)sv)[(b0w * 64 + r64) * 3 + 2];
        for (int w = 1; w < 4; ++w) {
            int base = ((b0w + w) * 64 + r64) * 3;
            float ob = sv[base], os = sv[base + 1];
            int oi = ((int*)sv)[base + 2];
            if (ob > b0) { s0 = fmaxf(b0, os); b0 = ob; i0 = oi; }
            else s0 = fmaxf(s0, ob);
        }
        out_idx[R0 + t] = (float)i0;
        fidx[t] = i0;
        if (b0 - s0 < MARGIN) {
            int pos = atomicAdd(counter, 1);
            list[pos] = R0 + t;
        }
    }
    __syncthreads();

    // ---- fused gather: 128 rows x 32 float4 = 8 per thread ----
    {
        const float4* eg = (const float4*)embed;
        float4* og = (float4*)(out_q + (size_t)R0 * DIM);
#pragma unroll
        for (int i = 0; i < 8; ++i) {
            int f = i * 512 + t;
            int r = f >> 5, cc = f & 31;
            og[(size_t)r * 32 + cc] = eg[(size_t)fidx[r] * 32 + cc];
        }
    }
}

// Compacted exact fp32 refine (16 flagged rows x 1024 bins per tile), with
// fused gather for its rows. First-max tie-break = reference semantics.
#define SWB(r, c4) ((r) * 128 + 4 * ((c4) ^ ((r) & 31)))
__global__ __launch_bounds__(256) void refine_kernel(const float* __restrict__ x,
                                                     const float* __restrict__ embed,
                                                     const float* __restrict__ esq_g,
                                                     float* __restrict__ out_idx,
                                                     float* __restrict__ out_q,
                                                     const int* __restrict__ list,
                                                     const int* __restrict__ counter) {
    __shared__ float xr[16 * 128];    // 8 KB
    __shared__ float bs[64 * 128];    // 32 KB
    __shared__ int rowbuf[16];
    __shared__ int ridx[16];

    const int t = threadIdx.x;
    const int tx = t & 63;
    const int ty = t >> 6;
    const int F = *counter;

    for (int tile = blockIdx.x; tile * 16 < F; tile += gridDim.x) {
        const int base = tile * 16;
        __syncthreads();
        if (t < 16) rowbuf[t] = list[min(base + t, F - 1)];
        __syncthreads();
#pragma unroll
        for (int i = 0; i < 2; ++i) {
            int f = i * 256 + t;
            int r = f >> 5, cc = f & 31;
            float4 v = ((const float4*)(x + (size_t)rowbuf[r] * DIM))[cc];
            *(float4*)&xr[r * 128 + cc * 4] = v;
        }

        float bb[4]; int bi[4];
#pragma unroll
        for (int rr = 0; rr < 4; ++rr) { bb[rr] = -3.4e38f; bi[rr] = 0; }

        for (int chunk = 0; chunk < 16; ++chunk) {
            __syncthreads();
            const float4* eg = (const float4*)(embed + (size_t)chunk * 64 * DIM);
#pragma unroll
            for (int i = 0; i < 8; ++i) {
                int f = i * 256 + t;
                int r = f >> 5, cc = f & 31;
                float4 v = eg[f];
                *(float4*)&bs[SWB(r, cc)] = v;
            }
            __syncthreads();

            float acc[4];
#pragma unroll
            for (int rr = 0; rr < 4; ++rr) acc[rr] = 0.f;
#pragma unroll 8
            for (int k4 = 0; k4 < 32; ++k4) {
                float4 b = *(const float4*)&bs[SWB(tx, k4)];
#pragma unroll
                for (int rr = 0; rr < 4; ++rr) {
                    float4 a = *(const float4*)&xr[(4 * ty + rr) * 128 + k4 * 4];
                    acc[rr] = fmaf(a.x, b.x, acc[rr]);
                    acc[rr] = fmaf(a.y, b.y, acc[rr]);
                    acc[rr] = fmaf(a.z, b.z, acc[rr]);
                    acc[rr] = fmaf(a.w, b.w, acc[rr]);
                }
            }
            const int bin = chunk * 64 + tx;
            const float e2 = esq_g[bin];
#pragma unroll
            for (int rr = 0; rr < 4; ++rr) {
                float sc = 2.f * acc[rr] - e2;
                if (sc > bb[rr]) { bb[rr] = sc; bi[rr] = bin; }
            }
        }

        __syncthreads();
        float* vals = bs;
        int* idxs = (int*)(bs + 1024);
#pragma unroll
        for (int rr = 0; rr < 4; ++rr) {
            vals[(4 * ty + rr) * 64 + tx] = bb[rr];
            idxs[(4 * ty + rr) * 64 + tx] = bi[rr];
        }
        __syncthreads();
        if (t < 16) {
            float bv = vals[t * 64];
            int bix = idxs[t * 64];
            for (int j = 1; j < 64; ++j) {
                float v = vals[t * 64 + j];
                int id = idxs[t * 64 + j];
                if (v > bv || (v == bv && id < bix)) { bv = v; bix = id; }
            }
            ridx[t] = bix;
            if (base + t < F) out_idx[rowbuf[t]] = (float)bix;
        }
        __syncthreads();
        // fused gather for this tile's rows (dup tail rows rewrite same data)
        {
            const float4* eg = (const float4*)embed;
#pragma unroll
            for (int i = 0; i < 2; ++i) {
                int f = i * 256 + t;
                int r = f >> 5, cc = f & 31;
                float4* og = (float4*)(out_q + (size_t)rowbuf[r] * DIM);
                og[cc] = eg[(size_t)ridx[r] * 32 + cc];
            }
        }
    }
}

extern "C" void kernel_launch(void* const* d_in, const int* in_sizes, int n_in,
                              void* d_out, int out_size, void* d_ws, size_t ws_size,
                              hipStream_t stream) {
    const float* x = (const float*)d_in[0];
    const float* embed = (const float*)d_in[1];
    float* out_q = (float*)d_out;
    float* out_idx = out_q + (size_t)N_ROWS * DIM;
    char* wsb = (char*)d_ws;
    _Float16* e_img = (_Float16*)wsb;                         // 256 KB (16 x 16 KB)
    float* esq_g = (float*)(wsb + (16 << 14));                // 4 KB
    int* counter = (int*)(wsb + (16 << 14) + 4096);           // 4 B (+pad)
    int* list = (int*)(wsb + (16 << 14) + 4096 + 128);        // 512 KB

    prep_kernel<<<BINS / 256, 256, 0, stream>>>(embed, e_img, esq_g, counter);
    vq_mfma_kernel<<<N_ROWS / 128, 512, 0, stream>>>(x, e_img, esq_g, embed,
                                                     out_idx, out_q, list, counter);
    refine_kernel<<<1024, 256, 0, stream>>>(x, embed, esq_g, out_idx, out_q, list, counter);
}